// Round 11
// baseline (98.189 us; speedup 1.0000x reference)
//
#include <hip/hip_runtime.h>
#include <hip/hip_fp16.h>

// Deformable Conv2d — MI355X, round 11
// vs round 10: same per-wave work, but blocks tile 4 rows x 64 cols so the
// LDS window shrinks 49.3 KB -> 18 KB (15 rows x 75 cols, margin 5 in y AND
// x). LDS now allows 9 blocks/CU; VGPR caps at ~28 waves/CU vs R10's 12 —
// the first real occupancy increase with independent (4-wave) blocks.
// R8's "24 waves" was actually 2 blocks/CU (53.76 KB > 160/3); R9 coupled 16
// waves on one barrier. Staged traffic also drops 404 -> 146 MB.

#define KSZ 3
#define PAD 1

static constexpr int B   = 4;
static constexpr int Cin = 64;
static constexpr int H   = 256;
static constexpr int W   = 256;
static constexpr int G   = 8;
static constexpr int OC  = 64;
static constexpr int KK  = KSZ * KSZ;  // 9
static constexpr int Cpg = Cin / G;    // 8
static constexpr int OPG = OC / G;     // 8
static constexpr int HW  = H * W;
static constexpr int NXCD = 8;

static constexpr int BR    = 4;        // output rows per block
static constexpr int BC    = 64;       // output cols per block
static constexpr int MARG  = 5;
static constexpr int WROWS = BR + 2 * MARG + 1;  // 15
static constexpr int WCOLS = 75;                 // 74 used + 1 spare
static constexpr int WUSED = BC + 2 * MARG;      // 74

typedef _Float16 f16x8  __attribute__((ext_vector_type(8)));
typedef float    f32x16 __attribute__((ext_vector_type(16)));

union U4H {
    uint4 u;
    __half2 h2[4];
    _Float16 h[8];
    f16x8 v;
};

// ---- transpose: x [B,Cin,H,W] f32 -> xt [B,G,H,W,Cpg] fp16 (16B/pixel) ----
__global__ __launch_bounds__(256) void transpose_kernel(
    const float* __restrict__ x, uint4* __restrict__ xt)
{
    const int h = blockIdx.x, g = blockIdx.y, b = blockIdx.z;
    const int w = threadIdx.x;
    const int pix = h * W + w;
    const float* src = x + (size_t)(b * Cin + g * Cpg) * HW + pix;
    U4H v;
#pragma unroll
    for (int c = 0; c < 8; ++c) v.h[c] = (_Float16)src[(size_t)c * HW];
    xt[(size_t)(b * G + g) * HW + pix] = v.u;
}

// ---- prep: per-lane MFMA A-fragments, layout [g][m][lane] (40 KB) ----
__global__ __launch_bounds__(320) void prep_weights(
    const float* __restrict__ weight, uint4* __restrict__ wfrag)
{
    const int g    = blockIdx.x;
    const int tid  = threadIdx.x;     // 0..319
    const int m    = tid >> 6;        // 0..4
    const int lane = tid & 63;
    const int hi   = lane >> 5;
    const int lp   = lane & 31;
    const int t    = 2 * m + hi;
    U4H a;
#pragma unroll
    for (int c = 0; c < 8; ++c) {
        float v = 0.0f;
        if (lp < OPG && t < KK)
            v = weight[((size_t)(g * OPG + lp) * Cpg + c) * KK + t];
        a.h[c] = (_Float16)v;
    }
    wfrag[((size_t)g * 5 + m) * 64 + lane] = a.u;
}

// ---- main kernel: 256 threads, 4 rows x 64 cols per block ----
__global__ __launch_bounds__(256) void dcn_kernel(
    const uint4* __restrict__ xt,
    const uint4* __restrict__ wfrag,
    const float* __restrict__ offset,
    const float* __restrict__ mask,
    const float* __restrict__ bias,
    float* __restrict__ out)
{
    __shared__ uint4 win[WROWS * WCOLS];   // 18,000 B

    // XCD-chunked bijective swizzle (8192 blocks % 8 == 0)
    const unsigned id = blockIdx.x;
    const unsigned wl = (id & (NXCD - 1)) * (gridDim.x / NXCD) + (id >> 3);
    const int colblk = wl & 3;                // 0..3
    const int rowblk = (wl >> 2) & 63;        // 0..63
    const int g      = (wl >> 8) & (G - 1);
    const int b      = wl >> 11;

    const int h_base = rowblk * BR;
    const int xbase  = colblk * BC;
    const int h0     = h_base - MARG;
    const int x0base = xbase - MARG;

    const int tid  = threadIdx.x;
    const int lane = tid & 63;
    const int wave = tid >> 6;                // 0..3 -> output row
    const int hi   = lane >> 5;               // tap parity in MFMA k dim
    const int lp   = lane & 31;               // A-row (out ch) / B-col (pixel)

    const int h = h_base + wave;

    const uint4* xb = xt + (size_t)(b * G + g) * HW;

    // ---- stage the 15x74 window (rows+cols pre-clamped) ----
#pragma unroll
    for (int it = 0; it < 5; ++it) {
        const int k = it * 256 + tid;
        if (k < WROWS * WCOLS) {
            const int i = k / WCOLS;
            const int j = k - i * WCOLS;
            const int gr = min(max(h0 + i, 0), H - 1);
            const int gc = min(max(x0base + j, 0), W - 1);
            win[k] = xb[gr * W + gc];
        }
    }

    // A-fragments: 5 coalesced dwordx4 loads (precomputed by prep_weights)
    f16x8 afrag[5];
    {
        const uint4* wf = wfrag + (size_t)g * 5 * 64 + lane;
#pragma unroll
        for (int m = 0; m < 5; ++m) {
            U4H tmp; tmp.u = wf[m * 64];
            afrag[m] = tmp.v;
        }
    }

    const float* offy = offset + (size_t)(b * 2 + 0) * (G * KK) * HW;
    const float* offx = offset + (size_t)(b * 2 + 1) * (G * KK) * HW;
    const float* mk   = mask + (size_t)b * (G * KK) * HW;

    // burst all offset/mask loads (sigmoid + tap-9 pad folded here)
    float dyv[2][5], dxv[2][5], msv[2][5];
#pragma unroll
    for (int tile = 0; tile < 2; ++tile) {
        const int wq  = xbase + tile * 32 + lp;
        const int pix = h * W + wq;
#pragma unroll
        for (int m = 0; m < 5; ++m) {
            const int t  = 2 * m + hi;
            const int tt = (t > 8) ? 8 : t;
            const int idx0 = G * KK - 1 - (g * KK + tt);   // flipped tap axis
            dyv[tile][m] = offy[(size_t)idx0 * HW + pix];
            dxv[tile][m] = offx[(size_t)idx0 * HW + pix];
            const float mv = mk[(size_t)(g * KK + tt) * HW + pix];
            float s = 1.0f / (1.0f + __expf(-mv));
            msv[tile][m] = (t <= 8) ? s : 0.0f;
        }
    }

    __syncthreads();   // window ready

    // one tap: bilinear blend of 4 corners from the LDS window
    auto sample = [&](int t, int wq, float dy, float dx, float msig) -> f16x8 {
        const int tt = (t > 8) ? 8 : t;
        const int ki = (tt >= 3) + (tt >= 6);
        const int kj = tt - 3 * ki;

        const float py = (float)(h - PAD + ki) + dy;
        const float px = (float)(wq - PAD + kj) + dx;
        const float y0f = floorf(py), x0f = floorf(px);
        const float wy = py - y0f, wx = px - x0f;
        const int y0 = (int)y0f, x0 = (int)x0f;
        const int iy0 = y0 - h0;               // local row
        const int ix0 = x0 - x0base;           // local col

        float w00, w01, w10, w11;
        uint4 v00, v01, v10, v11;

        const bool ok = (y0 >= 0) & (y0 + 1 < H) & (x0 >= 0) & (x0 + 1 < W) &
                        ((unsigned)iy0 <= (unsigned)(WROWS - 2)) &
                        ((unsigned)ix0 <= (unsigned)(WUSED - 2));
        if (__all((int)ok)) {
            // interior fast path: no clamps, no validity masks
            const float u = (1.f - wy) * msig, v = wy * msig;
            w00 = u * (1.f - wx); w01 = u * wx;
            w10 = v * (1.f - wx); w11 = v * wx;
            const int a0 = iy0 * WCOLS + ix0;
            v00 = win[a0];         v01 = win[a0 + 1];
            v10 = win[a0 + WCOLS]; v11 = win[a0 + WCOLS + 1];
        } else {
            const bool vy0 = (y0 >= 0) & (y0 < H), vy1 = (y0 + 1 >= 0) & (y0 + 1 < H);
            const bool vx0 = (x0 >= 0) & (x0 < W), vx1 = (x0 + 1 >= 0) & (x0 + 1 < W);
            const float u   = vy0 ? (1.f - wy) * msig : 0.f;
            const float v   = vy1 ? wy * msig : 0.f;
            const float cx0 = vx0 ? (1.f - wx) : 0.f;
            const float cx1 = vx1 ? wx : 0.f;
            w00 = u * cx0; w01 = u * cx1; w10 = v * cx0; w11 = v * cx1;

            const int i0  = min(max(iy0, 0), WROWS - 1);
            const int i1  = min(max(iy0 + 1, 0), WROWS - 1);
            const int jx0 = min(max(ix0, 0), WUSED - 1);
            const int jx1 = min(max(ix0 + 1, 0), WUSED - 1);
            v00 = win[i0 * WCOLS + jx0];
            v01 = win[i0 * WCOLS + jx1];
            v10 = win[i1 * WCOLS + jx0];
            v11 = win[i1 * WCOLS + jx1];

            // valid-but-outside-window (rare: |offset| > ~4) -> global fallback
            const bool bad =
                (vy0 & ((unsigned)iy0 > (unsigned)(WROWS - 1))) |
                (vy1 & ((unsigned)(iy0 + 1) > (unsigned)(WROWS - 1))) |
                (vx0 & ((unsigned)ix0 > (unsigned)(WUSED - 1))) |
                (vx1 & ((unsigned)(ix0 + 1) > (unsigned)(WUSED - 1)));
            if (__builtin_expect(__any((int)bad), 0)) {
                if (bad) {
                    const int yc0 = min(max(y0, 0), H - 1);
                    const int yc1 = min(max(y0 + 1, 0), H - 1);
                    const int xc0 = min(max(x0, 0), W - 1);
                    const int xc1 = min(max(x0 + 1, 0), W - 1);
                    v00 = xb[yc0 * W + xc0];
                    v01 = xb[yc0 * W + xc1];
                    v10 = xb[yc1 * W + xc0];
                    v11 = xb[yc1 * W + xc1];
                }
            }
        }

        U4H a, bq, c, d; a.u = v00; bq.u = v01; c.u = v10; d.u = v11;
        const __half2 hw00 = __float2half2_rn(w00);
        const __half2 hw01 = __float2half2_rn(w01);
        const __half2 hw10 = __float2half2_rn(w10);
        const __half2 hw11 = __float2half2_rn(w11);
        U4H s;
#pragma unroll
        for (int i = 0; i < 4; ++i)
            s.h2[i] = __hfma2(hw00, a.h2[i],
                      __hfma2(hw01, bq.h2[i],
                      __hfma2(hw10, c.h2[i],
                      __hmul2(hw11, d.h2[i]))));
        return s.v;
    };

    f32x16 acc0 = {};
    f32x16 acc1 = {};
    {
        const int wq = xbase + lp;
#pragma unroll
        for (int m = 0; m < 5; ++m)
            acc0 = __builtin_amdgcn_mfma_f32_32x32x16_f16(
                afrag[m], sample(2 * m + hi, wq, dyv[0][m], dxv[0][m], msv[0][m]), acc0, 0, 0, 0);
    }
    {
        const int wq = xbase + 32 + lp;
#pragma unroll
        for (int m = 0; m < 5; ++m)
            acc1 = __builtin_amdgcn_mfma_f32_32x32x16_f16(
                afrag[m], sample(2 * m + hi, wq, dyv[1][m], dxv[1][m], msv[1][m]), acc1, 0, 0, 0);
    }

    // C layout: col = lp (pixel), row = (reg&3) + 8*(reg>>2) + 4*hi.
    // Useful rows 0..7 -> out channel d = reg + 4*hi (regs 0..3).
#pragma unroll
    for (int tile = 0; tile < 2; ++tile) {
        const int wq = xbase + tile * 32 + lp;
#pragma unroll
        for (int r = 0; r < 4; ++r) {
            const int dd = r + 4 * hi;
            const float v = (tile == 0 ? acc0[r] : acc1[r]) + bias[g * OPG + dd];
            out[((size_t)b * OC + g * OPG + dd) * HW + h * W + wq] = v;
        }
    }
}

extern "C" void kernel_launch(void* const* d_in, const int* in_sizes, int n_in,
                              void* d_out, int out_size, void* d_ws, size_t ws_size,
                              hipStream_t stream) {
    const float* x      = (const float*)d_in[0];
    const float* offset = (const float*)d_in[1];
    const float* mask   = (const float*)d_in[2];
    const float* weight = (const float*)d_in[3];
    const float* bias   = (const float*)d_in[4];
    float* out = (float*)d_out;

    uint4* xt    = (uint4*)d_ws;                                      // 32 MiB
    uint4* wfrag = (uint4*)((char*)d_ws + (size_t)B * G * HW * 16);   // 40 KiB

    dim3 tgrid(H, G, B);
    transpose_kernel<<<tgrid, dim3(256), 0, stream>>>(x, xt);
    prep_weights<<<dim3(G), dim3(320), 0, stream>>>(weight, wfrag);
    dcn_kernel<<<dim3(B * G * (H / BR) * (W / BC)), dim3(256), 0, stream>>>(
        xt, wfrag, offset, mask, bias, out);
}